// Round 7
// baseline (744.934 us; speedup 1.0000x reference)
//
#include <hip/hip_runtime.h>

// ---------------------------------------------------------------------------
// Kimi MLA attention block, MI355X (gfx950).  Round 7:
//  gemm256 rebuilt as a DEEP pipeline: BK=32, 4 LDS buffers (128KB),
//  stage tile t+3 at iter t (3-tile prefetch distance ~= 1000cy, covers HBM),
//  ONE raw s_barrier + ONE counted vmcnt(8) per K-tile, no phase barriers.
//  Fragment-contiguous LDS (0 conflicts, r6-proven). Template<BM>: Wo uses
//  BM=128 so its grid is 256 blocks (100% fill, was 50%).
//  attn_k = round-2 proven version; kva = m97-style gemm_bt.
// ---------------------------------------------------------------------------

typedef __bf16 bf16x8 __attribute__((ext_vector_type(8)));
typedef float f32x4 __attribute__((ext_vector_type(4)));

#define SEQLEN 2048
#define NH 32
#define QH 192
#define QN 6144   // NH*QH
#define KVN 8192  // NH*256
#define HID 4096
#define CKVP 640  // padded 512+64 -> 640

#define AS1 __attribute__((address_space(1)))
#define AS3 __attribute__((address_space(3)))

__device__ __forceinline__ unsigned short f2b(float f) {
  union { float f; unsigned int u; } x; x.f = f;
  unsigned int r = (x.u + 0x7FFFu + ((x.u >> 16) & 1u)) >> 16;
  return (unsigned short)r;
}
__device__ __forceinline__ float b2f(unsigned short b) {
  union { unsigned int u; float f; } x; x.u = ((unsigned int)b) << 16;
  return x.f;
}

// ---- elementwise f32 -> bf16 (vectorized) ----
__global__ __launch_bounds__(256) void convk(const float* __restrict__ in,
                                             unsigned short* __restrict__ out,
                                             int n4) {
  int i = blockIdx.x * 256 + threadIdx.x;
  if (i < n4) {
    float4 v = ((const float4*)in)[i];
    ushort4 o;
    o.x = f2b(v.x); o.y = f2b(v.y); o.z = f2b(v.z); o.w = f2b(v.w);
    ((ushort4*)out)[i] = o;
  }
}

// ---- transpose+convert: out[c][r] = bf16(in[r][c]) for c<Cin else 0 ----
__global__ __launch_bounds__(256) void tconv(const float* __restrict__ in,
                                             unsigned short* __restrict__ out,
                                             int R, int Cin, int Cp) {
  __shared__ float t[64][65];
  const int r0 = blockIdx.x * 64, c0 = blockIdx.y * 64;
  const int tid = threadIdx.x;
#pragma unroll
  for (int i = 0; i < 16; ++i) {
    int idx = tid + i * 256;
    int rr = idx >> 6, cc = idx & 63;
    int c = c0 + cc;
    t[rr][cc] = (c < Cin) ? in[(size_t)(r0 + rr) * Cin + c] : 0.f;
  }
  __syncthreads();
#pragma unroll
  for (int i = 0; i < 16; ++i) {
    int idx = tid + i * 256;
    int cc = idx >> 6, rr = idx & 63;
    out[(size_t)(c0 + cc) * R + (r0 + rr)] = f2b(t[rr][cc]);
  }
}

// ---- BMx256 deep-pipelined GEMM: C = A * B^T, bf16 in, fp32 acc ----
// 512 threads = 8 waves (2M x 4N). BM=256: wave out 128x64 (8x4 frags);
// BM=128: wave out 64x64 (4x4 frags). BK=32: one MFMA per frag per tile.
// 4 LDS buffers; iter t: vmcnt(8) [tile t landed; t+1,t+2 in flight] ->
// s_barrier -> stage(t+3) into buf (t+3)&3 (== (t-1)&3, readers retired) ->
// ds_read frags -> MFMA. 3-tile prefetch distance covers HBM latency.
// LDS 16B-unit u of a tile: row (u>>6)*16+(u&15), col ((u>>4)&3)*8
// (frag read = 64 lanes x contiguous 16B -> conflict-free; gload dest linear,
// source per-lane pre-permuted; rule #21).  [r6-verified mapping]
template <int BM, typename OutT>
__global__ __launch_bounds__(512, 2) void gemm256(const unsigned short* __restrict__ A,
                                                  const unsigned short* __restrict__ B,
                                                  OutT* __restrict__ C,
                                                  int M, int N, int K) {
  constexpr int MF = BM / 32;        // A frags per wave (8 or 4)
  constexpr int AUNITS = BM * 4;     // 16B units per A tile (BM*32*2/16)
  __shared__ __align__(16) unsigned short As[4][AUNITS * 8];  // BM=256: 64KB
  __shared__ __align__(16) unsigned short Bs[4][8192];        // 64KB
  const int tid = threadIdx.x;
  const int lane = tid & 63;
  const int w = tid >> 6;
  const int wr = w >> 2, wc = w & 3;
  const int l15 = lane & 15, lg = lane >> 4;
  const int ntn = N >> 8;
  const int bm = blockIdx.x / ntn, bn = blockIdx.x % ntn;
  const int m0 = bm * BM, n0 = bn << 8;

  auto stage = [&](int t) {
    const int b = t & 3;
    const int k0 = t << 5;
    if constexpr (BM == 256) {
#pragma unroll
      for (int r = 0; r < 2; ++r) {
        int u = r * 512 + tid;
        int row = ((u >> 6) << 4) | (u & 15), col = ((u >> 4) & 3) << 3;
        __builtin_amdgcn_global_load_lds(
            (const AS1 void*)(A + (size_t)(m0 + row) * K + (k0 + col)),
            (AS3 void*)(&As[b][u * 8]), 16, 0, 0);
      }
    } else {
      int u = tid;
      int row = ((u >> 6) << 4) | (u & 15), col = ((u >> 4) & 3) << 3;
      __builtin_amdgcn_global_load_lds(
          (const AS1 void*)(A + (size_t)(m0 + row) * K + (k0 + col)),
          (AS3 void*)(&As[b][u * 8]), 16, 0, 0);
    }
#pragma unroll
    for (int r = 0; r < 2; ++r) {
      int u = r * 512 + tid;
      int row = ((u >> 6) << 4) | (u & 15), col = ((u >> 4) & 3) << 3;
      __builtin_amdgcn_global_load_lds(
          (const AS1 void*)(B + (size_t)(n0 + row) * K + (k0 + col)),
          (AS3 void*)(&Bs[b][u * 8]), 16, 0, 0);
    }
  };

  const f32x4 zero4 = {0.f, 0.f, 0.f, 0.f};
  f32x4 acc[MF][4];
#pragma unroll
  for (int i = 0; i < MF; ++i)
#pragma unroll
    for (int j = 0; j < 4; ++j) acc[i][j] = zero4;

  const int nk = K >> 5;
  stage(0); stage(1); stage(2);  // 12 loads/thread in flight

#pragma unroll 1
  for (int t = 0; t < nk; ++t) {
    // per-wave counted wait; barrier then guarantees ALL waves' tile-t loads
    // landed (each wave passed its own vmcnt before arriving).
    if (t <= nk - 3) {
      asm volatile("s_waitcnt vmcnt(8)" ::: "memory");
    } else if (t == nk - 2) {
      asm volatile("s_waitcnt vmcnt(4)" ::: "memory");
    } else {
      asm volatile("s_waitcnt vmcnt(0)" ::: "memory");
    }
    __builtin_amdgcn_s_barrier();
    __builtin_amdgcn_sched_barrier(0);  // keep ds_reads below the barrier
    if (t + 3 < nk) stage(t + 3);       // buf (t+3)&3 == (t-1)&3: reads retired
    const int b = t & 3;
    bf16x8 aR[MF], bR[4];
#pragma unroll
    for (int mf = 0; mf < MF; ++mf)
      aR[mf] = *(const bf16x8*)&As[b][((wr * MF + mf) * 64 + lane) * 8];
#pragma unroll
    for (int nf = 0; nf < 4; ++nf)
      bR[nf] = *(const bf16x8*)&Bs[b][((wc * 4 + nf) * 64 + lane) * 8];
    __builtin_amdgcn_s_setprio(1);
#pragma unroll
    for (int mf = 0; mf < MF; ++mf)
#pragma unroll
      for (int nf = 0; nf < 4; ++nf)
        acc[mf][nf] = __builtin_amdgcn_mfma_f32_16x16x32_bf16(aR[mf], bR[nf], acc[mf][nf], 0, 0, 0);
    __builtin_amdgcn_s_setprio(0);
    __builtin_amdgcn_sched_barrier(0);  // keep this tile's work in its slot
  }

  // epilogue; C/D layout: col = lane&15, row = (lane>>4)*4 + i   [m89-verified]
  const int r0 = m0 + wr * (BM / 2), c0 = n0 + wc * 64;
#pragma unroll
  for (int mf = 0; mf < MF; ++mf)
#pragma unroll
    for (int nf = 0; nf < 4; ++nf) {
      int r = r0 + mf * 16 + lg * 4;
      int c = c0 + nf * 16 + l15;
#pragma unroll
      for (int i = 0; i < 4; ++i) {
        float v = acc[mf][nf][i];
        if constexpr (sizeof(OutT) == 2)
          ((unsigned short*)C)[(size_t)(r + i) * N + c] = f2b(v);
        else
          ((float*)C)[(size_t)(r + i) * N + c] = v;
      }
    }
}

// ---- 128x128 GEMM (m97 structure) for the small kva matmul ----
template <typename OutT>
__global__ __launch_bounds__(256) void gemm_bt(const unsigned short* __restrict__ A,
                                               const unsigned short* __restrict__ B,
                                               OutT* __restrict__ C,
                                               int M, int N, int K) {
  __shared__ __align__(16) unsigned short As[128 * 64];
  __shared__ __align__(16) unsigned short Bs[128 * 64];
  const int tid = threadIdx.x;
  const int lane = tid & 63;
  const int w = tid >> 6;
  const int wr = w >> 1, wc = w & 1;
  const int l15 = lane & 15, lg = lane >> 4;
  const int ntn = N >> 7;
  const int bm = blockIdx.x / ntn, bn = blockIdx.x % ntn;
  const int m0 = bm << 7, n0 = bn << 7;
  const int lrow = tid >> 3;
  const int lcol = (tid & 7) << 3;

  const f32x4 zero4 = {0.f, 0.f, 0.f, 0.f};
  f32x4 acc[4][4];
#pragma unroll
  for (int i = 0; i < 4; ++i)
#pragma unroll
    for (int j = 0; j < 4; ++j) acc[i][j] = zero4;

  for (int k0 = 0; k0 < K; k0 += 64) {
#pragma unroll
    for (int j = 0; j < 4; ++j) {
      const unsigned short* ga = A + (size_t)(m0 + j * 32 + lrow) * K + (k0 + lcol);
      const unsigned short* gb = B + (size_t)(n0 + j * 32 + lrow) * K + (k0 + lcol);
      __builtin_amdgcn_global_load_lds((const AS1 void*)ga,
                                       (AS3 void*)(&As[j * 2048 + w * 512]), 16, 0, 0);
      __builtin_amdgcn_global_load_lds((const AS1 void*)gb,
                                       (AS3 void*)(&Bs[j * 2048 + w * 512]), 16, 0, 0);
    }
    __syncthreads();
#pragma unroll
    for (int kk = 0; kk < 2; ++kk) {
      bf16x8 a[4], b[4];
#pragma unroll
      for (int m = 0; m < 4; ++m)
        a[m] = *(const bf16x8*)&As[(wr * 64 + m * 16 + l15) * 64 + kk * 32 + lg * 8];
#pragma unroll
      for (int n = 0; n < 4; ++n)
        b[n] = *(const bf16x8*)&Bs[(wc * 64 + n * 16 + l15) * 64 + kk * 32 + lg * 8];
#pragma unroll
      for (int m = 0; m < 4; ++m)
#pragma unroll
        for (int n = 0; n < 4; ++n)
          acc[m][n] = __builtin_amdgcn_mfma_f32_16x16x32_bf16(a[m], b[n], acc[m][n], 0, 0, 0);
    }
    __syncthreads();
  }
  const int r0 = m0 + wr * 64, c0 = n0 + wc * 64;
#pragma unroll
  for (int m = 0; m < 4; ++m)
#pragma unroll
    for (int n = 0; n < 4; ++n) {
      int r = r0 + m * 16 + lg * 4;
      int c = c0 + n * 16 + l15;
#pragma unroll
      for (int i = 0; i < 4; ++i) {
        float v = acc[m][n][i];
        if constexpr (sizeof(OutT) == 2)
          ((unsigned short*)C)[(size_t)(r + i) * N + c] = f2b(v);
        else
          ((float*)C)[(size_t)(r + i) * N + c] = v;
      }
    }
}

// ---- RMSNorm over ckv[:, :512] -> bf16 ----
__global__ __launch_bounds__(256) void rmsnorm_k(const float* __restrict__ ckv,
                                                 const float* __restrict__ w,
                                                 unsigned short* __restrict__ out) {
  const int s = blockIdx.x;
  const int tid = threadIdx.x;
  const float* row = ckv + (size_t)s * CKVP;
  float x0 = row[tid], x1 = row[tid + 256];
  float ss = x0 * x0 + x1 * x1;
#pragma unroll
  for (int o = 1; o < 64; o <<= 1) ss += __shfl_xor(ss, o, 64);
  __shared__ float red[4];
  if ((tid & 63) == 0) red[tid >> 6] = ss;
  __syncthreads();
  float rs = rsqrtf((red[0] + red[1] + red[2] + red[3]) * (1.f / 512.f) + 1e-6f);
  out[(size_t)s * 512 + tid] = f2b(w[tid] * x0 * rs);
  out[(size_t)s * 512 + tid + 256] = f2b(w[tid + 256] * x1 * rs);
}

// ---- RoPE on q rot part (in place, bf16) ----
__global__ __launch_bounds__(256) void rope_q_k(unsigned short* __restrict__ q) {
  int idx = blockIdx.x * 256 + threadIdx.x;  // 2048*32*32
  int i = idx & 31, h = (idx >> 5) & 31, s = idx >> 10;
  float inv = exp2f(-(float)i * 0.4152410118609203f);  // 10000^(-i/32)
  float ang = (float)s * inv;
  float c = cosf(ang), sn = sinf(ang);
  size_t base = (size_t)s * QN + h * QH + 128;
  float x1 = b2f(q[base + i]), x2 = b2f(q[base + 32 + i]);
  q[base + i] = f2b(x1 * c - x2 * sn);
  q[base + 32 + i] = f2b(x2 * c + x1 * sn);
}

// ---- RoPE on shared k rot part (f32 src) -> kr bf16 (2048x64) ----
__global__ __launch_bounds__(256) void rope_k_k(const float* __restrict__ ckv,
                                                unsigned short* __restrict__ kr) {
  int idx = blockIdx.x * 256 + threadIdx.x;  // 2048*32
  int i = idx & 31, s = idx >> 5;
  float inv = exp2f(-(float)i * 0.4152410118609203f);
  float ang = (float)s * inv;
  float c = cosf(ang), sn = sinf(ang);
  const float* row = ckv + (size_t)s * CKVP + 512;
  float x1 = row[i], x2 = row[32 + i];
  kr[(size_t)s * 64 + i] = f2b(x1 * c - x2 * sn);
  kr[(size_t)s * 64 + 32 + i] = f2b(x2 * c + x1 * sn);
}

// ---- per-head V transpose: vT[h][v][t] = kv[t][h*256+128+v] ----
__global__ __launch_bounds__(256) void tv_k(const unsigned short* __restrict__ kv,
                                            unsigned short* __restrict__ vT) {
  __shared__ unsigned short t[64][66];
  const int t0 = blockIdx.x * 64, v0 = blockIdx.y * 64, h = blockIdx.z;
  const int tid = threadIdx.x;
#pragma unroll
  for (int i = 0; i < 16; ++i) {
    int idx = tid + i * 256;
    int rr = idx >> 6, cc = idx & 63;
    t[rr][cc] = kv[(size_t)(t0 + rr) * KVN + h * 256 + 128 + v0 + cc];
  }
  __syncthreads();
#pragma unroll
  for (int i = 0; i < 16; ++i) {
    int idx = tid + i * 256;
    int cc = idx >> 6, rr = idx & 63;
    vT[((size_t)h * 128 + v0 + cc) * SEQLEN + t0 + rr] = t[rr][cc];
  }
}

// ---- causal flash attention (round-2 proven structure) ----
// grid (8, 32): block bx handles q-tiles {bx, 15-bx} (128 rows each) of head
// blockIdx.y. 4 waves x 32 q-rows. KV tile = 64, async reg-staged.
__global__ __launch_bounds__(256) void attn_k(const unsigned short* __restrict__ q,
                                              const unsigned short* __restrict__ kv,
                                              const unsigned short* __restrict__ kr,
                                              const unsigned short* __restrict__ vT,
                                              unsigned short* __restrict__ ao) {
  __shared__ __align__(16) unsigned short Kt[64 * 192];   // 24 KB
  __shared__ __align__(16) unsigned short Vt[128 * 72];   // 18 KB
  __shared__ __align__(16) unsigned short Pl[4][32 * 72]; // 18 KB (per-wave)

  const int tid = threadIdx.x;
  const int lane = tid & 63;
  const int w = tid >> 6;
  const int l15 = lane & 15, lg = lane >> 4;
  const int sw = l15 & 7;
  const int h = blockIdx.y;
  const float scale = 0.07216878364870323f;  // 192^-0.5
  const f32x4 zero4 = {0.f, 0.f, 0.f, 0.f};

  bf16x8 kregs[4], rregs[2], vregs[4];

  auto loadregs = [&](int t0) {
#pragma unroll
    for (int p = 0; p < 4; ++p) {
      int id = tid + p * 256;
      kregs[p] = *(const bf16x8*)&kv[(size_t)(t0 + (id >> 4)) * KVN + h * 256 + (id & 15) * 8];
    }
#pragma unroll
    for (int p = 0; p < 2; ++p) {
      int id = tid + p * 256;
      rregs[p] = *(const bf16x8*)&kr[(size_t)(t0 + (id >> 3)) * 64 + (id & 7) * 8];
    }
#pragma unroll
    for (int p = 0; p < 4; ++p) {
      int id = tid + p * 256;
      vregs[p] = *(const bf16x8*)&vT[((size_t)h * 128 + (id >> 3)) * SEQLEN + t0 + (id & 7) * 8];
    }
  };
  auto writelds = [&]() {
#pragma unroll
    for (int p = 0; p < 4; ++p) {
      int id = tid + p * 256;
      int r = id >> 4, c16 = id & 15;
      *(bf16x8*)&Kt[r * 192 + ((c16 ^ (r & 7)) << 3)] = kregs[p];
    }
#pragma unroll
    for (int p = 0; p < 2; ++p) {
      int id = tid + p * 256;
      int r = id >> 3;
      *(bf16x8*)&Kt[r * 192 + ((16 + ((id & 7) ^ (r & 7))) << 3)] = rregs[p];
    }
#pragma unroll
    for (int p = 0; p < 4; ++p) {
      int id = tid + p * 256;
      *(bf16x8*)&Vt[(id >> 3) * 72 + (id & 7) * 8] = vregs[p];
    }
  };

#pragma unroll 1
  for (int pass = 0; pass < 2; ++pass) {
    const int qt = pass ? (15 - (int)blockIdx.x) : (int)blockIdx.x;
    const int n_it = 2 * qt + 2;
    const int qrow_base = qt * 128 + w * 32;

    bf16x8 qf[2][6];
#pragma unroll
    for (int m = 0; m < 2; ++m) {
      const size_t qoff = (size_t)(qrow_base + m * 16 + l15) * QN + (size_t)h * QH + lg * 8;
#pragma unroll
      for (int c = 0; c < 6; ++c) qf[m][c] = *(const bf16x8*)(q + qoff + c * 32);
    }

    f32x4 o[2][8];
    float m_r[2][4], s_r[2][4];
#pragma unroll
    for (int m = 0; m < 2; ++m) {
#pragma unroll
      for (int vt = 0; vt < 8; ++vt) o[m][vt] = zero4;
#pragma unroll
      for (int i = 0; i < 4; ++i) { m_r[m][i] = -1e30f; s_r[m][i] = 0.f; }
    }

    loadregs(0);

#pragma unroll 1
    for (int it = 0; it < n_it; ++it) {
      const int t0 = it * 64;
      writelds();
      __syncthreads();
      if (it + 1 < n_it) loadregs((it + 1) * 64);

      f32x4 st[2][4];
      __builtin_amdgcn_s_setprio(1);
#pragma unroll
      for (int tt = 0; tt < 4; ++tt) {
        f32x4 c0 = zero4, c1 = zero4;
        const int krow = (tt * 16 + l15) * 192;
#pragma unroll
        for (int c = 0; c < 6; ++c) {
          bf16x8 kf = *(const bf16x8*)&Kt[krow + (((c * 4 + lg) ^ sw) << 3)];
          c0 = __builtin_amdgcn_mfma_f32_16x16x32_bf16(qf[0][c], kf, c0, 0, 0, 0);
          c1 = __builtin_amdgcn_mfma_f32_16x16x32_bf16(qf[1][c], kf, c1, 0, 0, 0);
        }
        st[0][tt] = c0; st[1][tt] = c1;
      }
      __builtin_amdgcn_s_setprio(0);

      const bool domask = (t0 + 63 > qrow_base);
#pragma unroll
      for (int m = 0; m < 2; ++m) {
        float mt[4] = {-1e30f, -1e30f, -1e30f, -1e30f};
#pragma unroll
        for (int tt = 0; tt < 4; ++tt) {
          int tg = t0 + tt * 16 + l15;
#pragma unroll
          for (int i = 0; i < 4; ++i) {
            float v = st[m][tt][i] * scale;
            if (domask) {
              int qg = qrow_base + m * 16 + lg * 4 + i;
              v = (tg > qg) ? -1e30f : v;
            }
            st[m][tt][i] = v;
            mt[i] = fmaxf(mt[i], v);
          }
        }
#pragma unroll
        for (int off = 1; off < 16; off <<= 1)
#pragma unroll
          for (int i = 0; i < 4; ++i) mt[i] = fmaxf(mt[i], __shfl_xor(mt[i], off, 64));

        float al[4], ps[4];
#pragma unroll
        for (int i = 0; i < 4; ++i) {
          float mn = fmaxf(m_r[m][i], mt[i]);
          al[i] = __expf(m_r[m][i] - mn);
          m_r[m][i] = mn;
          ps[i] = 0.f;
        }
#pragma unroll
        for (int tt = 0; tt < 4; ++tt)
#pragma unroll
          for (int i = 0; i < 4; ++i) {
            float p = __expf(st[m][tt][i] - m_r[m][i]);
            st[m][tt][i] = p;
            ps[i] += p;
          }
#pragma unroll
        for (int off = 1; off < 16; off <<= 1)
#pragma unroll
          for (int i = 0; i < 4; ++i) ps[i] += __shfl_xor(ps[i], off, 64);
#pragma unroll
        for (int i = 0; i < 4; ++i) s_r[m][i] = s_r[m][i] * al[i] + ps[i];

#pragma unroll
        for (int tt = 0; tt < 4; ++tt)
#pragma unroll
          for (int i = 0; i < 4; ++i)
            Pl[w][(m * 16 + lg * 4 + i) * 72 + tt * 16 + l15] = f2b(st[m][tt][i]);

#pragma unroll
        for (int vt = 0; vt < 8; ++vt)
#pragma unroll
          for (int i = 0; i < 4; ++i) o[m][vt][i] *= al[i];
      }

      bf16x8 pa[2][2];
#pragma unroll
      for (int m = 0; m < 2; ++m)
#pragma unroll
        for (int ks = 0; ks < 2; ++ks)
          pa[m][ks] = *(const bf16x8*)&Pl[w][(m * 16 + l15) * 72 + ks * 32 + lg * 8];
      __builtin_amdgcn_s_setprio(1);
#pragma unroll
      for (int vt = 0; vt < 8; ++vt) {
        bf16x8 b0 = *(const bf16x8*)&Vt[(vt * 16 + l15) * 72 + lg * 8];
        bf16x8 b1 = *(const bf16x8*)&Vt[(vt * 16 + l15) * 72 + 32 + lg * 8];
#pragma unroll
        for (int m = 0; m < 2; ++m) {
          o[m][vt] = __builtin_amdgcn_mfma_f32_16x16x32_bf16(pa[m][0], b0, o[m][vt], 0, 0, 0);
          o[m][vt] = __builtin_amdgcn_mfma_f32_16x16x32_bf16(pa[m][1], b1, o[m][vt], 0, 0, 0);
        }
      }
      __builtin_amdgcn_s_setprio(0);
      __syncthreads();
    }

#pragma unroll
    for (int m = 0; m < 2; ++m)
#pragma unroll
      for (int vt = 0; vt < 8; ++vt)
#pragma unroll
        for (int i = 0; i < 4; ++i) {
          int qg = qrow_base + m * 16 + lg * 4 + i;
          int col = h * 128 + vt * 16 + l15;
          ao[(size_t)qg * (NH * 128) + col] = f2b(o[m][vt][i] / s_r[m][i]);
        }
  }
}

extern "C" void kernel_launch(void* const* d_in, const int* in_sizes, int n_in,
                              void* d_out, int out_size, void* d_ws, size_t ws_size,
                              hipStream_t stream) {
  (void)in_sizes; (void)n_in; (void)out_size; (void)ws_size;
  const float* hs = (const float*)d_in[1];
  const float* Wq = (const float*)d_in[2];
  const float* Wkva = (const float*)d_in[3];
  const float* lnw = (const float*)d_in[4];
  const float* Wkvb = (const float*)d_in[5];
  const float* Wo = (const float*)d_in[6];
  float* out = (float*)d_out;
  char* ws = (char*)d_ws;

  constexpr size_t OFF_HSBF = 0;                                    // 2048x4096 bf16
  constexpr size_t OFF_WQT = OFF_HSBF + (size_t)2048 * 4096 * 2;    // 6144x4096 bf16
  constexpr size_t OFF_WKVAT = OFF_WQT + (size_t)6144 * 4096 * 2;   // 640x4096 bf16
  constexpr size_t OFF_WKVBT = OFF_WKVAT + (size_t)640 * 4096 * 2;  // 8192x512 bf16
  constexpr size_t OFF_WOT = OFF_WKVBT + (size_t)8192 * 512 * 2;    // 4096x4096 bf16
  constexpr size_t OFF_Q = OFF_WOT + (size_t)4096 * 4096 * 2;       // 2048x6144 bf16
  constexpr size_t OFF_CKV = OFF_Q + (size_t)2048 * 6144 * 2;       // 2048x640 f32
  constexpr size_t OFF_CKVN = OFF_CKV + (size_t)2048 * 640 * 4;     // 2048x512 bf16
  constexpr size_t OFF_KR = OFF_CKVN + (size_t)2048 * 512 * 2;      // 2048x64 bf16
  constexpr size_t OFF_KV = OFF_KR + (size_t)2048 * 64 * 2;         // 2048x8192 bf16
  constexpr size_t OFF_VT = OFF_KV + (size_t)2048 * 8192 * 2;       // 32x128x2048 bf16
  constexpr size_t OFF_AO = OFF_VT + (size_t)32 * 128 * 2048 * 2;   // 2048x4096 bf16

  unsigned short* hs_bf = (unsigned short*)(ws + OFF_HSBF);
  unsigned short* WqT = (unsigned short*)(ws + OFF_WQT);
  unsigned short* WkvaT = (unsigned short*)(ws + OFF_WKVAT);
  unsigned short* WkvbT = (unsigned short*)(ws + OFF_WKVBT);
  unsigned short* WoT = (unsigned short*)(ws + OFF_WOT);
  unsigned short* qbuf = (unsigned short*)(ws + OFF_Q);
  float* ckv = (float*)(ws + OFF_CKV);
  unsigned short* ckvn = (unsigned short*)(ws + OFF_CKVN);
  unsigned short* kr = (unsigned short*)(ws + OFF_KR);
  unsigned short* kvbuf = (unsigned short*)(ws + OFF_KV);
  unsigned short* vT = (unsigned short*)(ws + OFF_VT);
  unsigned short* ao = (unsigned short*)(ws + OFF_AO);

  convk<<<dim3(8192), 256, 0, stream>>>(hs, hs_bf, 2048 * 4096 / 4);
  tconv<<<dim3(64, 96), 256, 0, stream>>>(Wq, WqT, 4096, 6144, 6144);
  tconv<<<dim3(64, 10), 256, 0, stream>>>(Wkva, WkvaT, 4096, 576, 640);
  tconv<<<dim3(8, 128), 256, 0, stream>>>(Wkvb, WkvbT, 512, 8192, 8192);
  tconv<<<dim3(64, 64), 256, 0, stream>>>(Wo, WoT, 4096, 4096, 4096);

  gemm256<256, unsigned short><<<dim3(8 * 24), 512, 0, stream>>>(hs_bf, WqT, qbuf, 2048, 6144, 4096);
  gemm_bt<float><<<dim3(16 * 5), 256, 0, stream>>>(hs_bf, WkvaT, ckv, 2048, 640, 4096);
  rmsnorm_k<<<dim3(2048), 256, 0, stream>>>(ckv, lnw, ckvn);
  rope_k_k<<<dim3(256), 256, 0, stream>>>(ckv, kr);
  gemm256<256, unsigned short><<<dim3(8 * 32), 512, 0, stream>>>(ckvn, WkvbT, kvbuf, 2048, 8192, 512);
  rope_q_k<<<dim3(8192), 256, 0, stream>>>(qbuf);
  tv_k<<<dim3(32, 2, 32), 256, 0, stream>>>(kvbuf, vT);
  attn_k<<<dim3(8, 32), 256, 0, stream>>>(qbuf, kvbuf, kr, vT, ao);
  gemm256<128, float><<<dim3(16 * 16), 512, 0, stream>>>(ao, WoT, out, 2048, 4096, 4096);
}

// Round 8
// 658.132 us; speedup vs baseline: 1.1319x; 1.1319x over previous
//
#include <hip/hip_runtime.h>

// ---------------------------------------------------------------------------
// Kimi MLA attention block, MI355X (gfx950).  Round 8:
//  gemm8p = faithful port of the verified m201 8-phase 256^2 template:
//  2 K-tiles/iter, 8 phases {ds_read subtile | stage 1 half-tile | barrier |
//  lgkmcnt(0) | 16 MFMA | barrier}, counted vmcnt(4) ONLY at phases 4 and 8,
//  never draining in steady state. Frag-contiguous LDS (0 conflicts).
//  Ledger (per-wave FIFO, halves; verified WAR/RAW):
//   p1:st A(2i+1)h0  p2:st A(2i+1)h1  p3:st B(2i+2)h0  p4:st B(2i+2)h1+vmcnt(4)
//   p5:st A(2i+2)h0  p6:st A(2i+2)h1  p7:st B(2i+3)h0  p8:st B(2i+3)h1+vmcnt(4)
//   quadrant snake: p1(m0,n0) p2(m0,n1) p3(m1,n1) p4(m1,n0) per K-tile.
//  Wo uses BM=128 so its grid is 256 blocks (100% fill).
//  attn_k/kva/transposes unchanged (proven).
// ---------------------------------------------------------------------------

typedef __bf16 bf16x8 __attribute__((ext_vector_type(8)));
typedef float f32x4 __attribute__((ext_vector_type(4)));

#define SEQLEN 2048
#define NH 32
#define QH 192
#define QN 6144   // NH*QH
#define KVN 8192  // NH*256
#define HID 4096
#define CKVP 640  // padded 512+64 -> 640

#define AS1 __attribute__((address_space(1)))
#define AS3 __attribute__((address_space(3)))

__device__ __forceinline__ unsigned short f2b(float f) {
  union { float f; unsigned int u; } x; x.f = f;
  unsigned int r = (x.u + 0x7FFFu + ((x.u >> 16) & 1u)) >> 16;
  return (unsigned short)r;
}
__device__ __forceinline__ float b2f(unsigned short b) {
  union { unsigned int u; float f; } x; x.u = ((unsigned int)b) << 16;
  return x.f;
}

// ---- elementwise f32 -> bf16 (vectorized) ----
__global__ __launch_bounds__(256) void convk(const float* __restrict__ in,
                                             unsigned short* __restrict__ out,
                                             int n4) {
  int i = blockIdx.x * 256 + threadIdx.x;
  if (i < n4) {
    float4 v = ((const float4*)in)[i];
    ushort4 o;
    o.x = f2b(v.x); o.y = f2b(v.y); o.z = f2b(v.z); o.w = f2b(v.w);
    ((ushort4*)out)[i] = o;
  }
}

// ---- transpose+convert: out[c][r] = bf16(in[r][c]) for c<Cin else 0 ----
__global__ __launch_bounds__(256) void tconv(const float* __restrict__ in,
                                             unsigned short* __restrict__ out,
                                             int R, int Cin, int Cp) {
  __shared__ float t[64][65];
  const int r0 = blockIdx.x * 64, c0 = blockIdx.y * 64;
  const int tid = threadIdx.x;
#pragma unroll
  for (int i = 0; i < 16; ++i) {
    int idx = tid + i * 256;
    int rr = idx >> 6, cc = idx & 63;
    int c = c0 + cc;
    t[rr][cc] = (c < Cin) ? in[(size_t)(r0 + rr) * Cin + c] : 0.f;
  }
  __syncthreads();
#pragma unroll
  for (int i = 0; i < 16; ++i) {
    int idx = tid + i * 256;
    int cc = idx >> 6, rr = idx & 63;
    out[(size_t)(c0 + cc) * R + (r0 + rr)] = f2b(t[rr][cc]);
  }
}

// ---- MFMA quadrant helper (all register indices compile-time; rule #20) ----
template <int MH, int MHALF, int PAIR>
__device__ __forceinline__ void mmaq(f32x4 (*acc)[4], const bf16x8* aR, const bf16x8* bX) {
  __builtin_amdgcn_s_setprio(1);
#pragma unroll
  for (int i2 = 0; i2 < MH; ++i2)
#pragma unroll
    for (int kk = 0; kk < 2; ++kk)
#pragma unroll
      for (int j = 0; j < 2; ++j)
        acc[MHALF * MH + i2][PAIR * 2 + j] = __builtin_amdgcn_mfma_f32_16x16x32_bf16(
            aR[i2 * 2 + kk], bX[j * 2 + kk], acc[MHALF * MH + i2][PAIR * 2 + j], 0, 0, 0);
  __builtin_amdgcn_s_setprio(0);
}

#define PH_SYNC()                                        \
  __builtin_amdgcn_s_barrier();                          \
  asm volatile("s_waitcnt lgkmcnt(0)" ::: "memory");     \
  __builtin_amdgcn_sched_barrier(0)
#define PH_END() __builtin_amdgcn_s_barrier()

// ---- BMx256 8-phase GEMM: C[M,N] = A[M,K] * B[N,K]^T, bf16 in, fp32 acc ----
// 512 threads = 8 waves (2M x 4N). Per-wave out (BM/2)x64 = MF x 4 frags.
// K-tile 64; A halves = (BM/2) rows, B halves = 128 rows; each half staged by
// one phase (ARND/2 gload instrs per thread). LDS unit u of a half:
// frag = u>>6 (=mf*2+kk), lane l=u&63 -> row (u>>7)*16+(l&15),
// col (u>>6 &1)*32+(l>>4)*8 -> frag read = 64 lanes x contiguous 16B.
template <int BM, typename OutT>
__global__ __launch_bounds__(512, 2) void gemm8p(const unsigned short* __restrict__ A,
                                                 const unsigned short* __restrict__ B,
                                                 OutT* __restrict__ C,
                                                 int M, int N, int K) {
  constexpr int MF = BM / 32;   // per-wave m-frags (8 or 4)
  constexpr int MH = MF / 2;    // m-frags per quadrant
  constexpr int ARND = BM / 128;  // gload rounds per A half (2 or 1)
  __shared__ __align__(16) unsigned short As[2][2][BM * 32];  // [buf][half]
  __shared__ __align__(16) unsigned short Bs[2][2][8192];

  const int tid = threadIdx.x;
  const int lane = tid & 63;
  const int w = tid >> 6;
  const int wr = w >> 2, wc = w & 3;
  const int l15 = lane & 15, lg = lane >> 4;
  const int ntn = N >> 8;
  const int bm = blockIdx.x / ntn, bn = blockIdx.x % ntn;
  const int m0 = bm * BM, n0 = bn << 8;

  auto stA = [&](int t, int h) {
    const int buf = t & 1, k0 = t << 6;
#pragma unroll
    for (int r = 0; r < ARND; ++r) {
      int u = r * 512 + tid;
      int blk = u >> 6, l = u & 63;
      int row = (blk >> 1) * 16 + (l & 15);
      int col = (blk & 1) * 32 + ((l >> 4) << 3);
      __builtin_amdgcn_global_load_lds(
          (const AS1 void*)(A + (size_t)(m0 + h * (BM / 2) + row) * K + (k0 + col)),
          (AS3 void*)(&As[buf][h][u * 8]), 16, 0, 0);
    }
  };
  auto stB = [&](int t, int h) {
    const int buf = t & 1, k0 = t << 6;
#pragma unroll
    for (int r = 0; r < 2; ++r) {
      int u = r * 512 + tid;
      int blk = u >> 6, l = u & 63;
      int row = (blk >> 1) * 16 + (l & 15);
      int col = (blk & 1) * 32 + ((l >> 4) << 3);
      __builtin_amdgcn_global_load_lds(
          (const AS1 void*)(B + (size_t)(n0 + h * 128 + row) * K + (k0 + col)),
          (AS3 void*)(&Bs[buf][h][u * 8]), 16, 0, 0);
    }
  };

  const f32x4 zero4 = {0.f, 0.f, 0.f, 0.f};
  f32x4 acc[MF][4];
#pragma unroll
  for (int i = 0; i < MF; ++i)
#pragma unroll
    for (int j = 0; j < 4; ++j) acc[i][j] = zero4;

  bf16x8 aR[MF], bA[4], bB[4];
  // reg indices compile-time; mhalf/pair only feed LDS addresses
  auto ldA = [&](int buf, int mhalf) {
#pragma unroll
    for (int i2 = 0; i2 < MH; ++i2)
#pragma unroll
      for (int kk = 0; kk < 2; ++kk)
        aR[i2 * 2 + kk] =
            *(const bf16x8*)&As[buf][wr][(((mhalf * MH + i2) * 2 + kk) * 64 + lane) * 8];
  };
  auto ldB = [&](int buf, int pair, bf16x8* dst) {
#pragma unroll
    for (int j = 0; j < 2; ++j)
#pragma unroll
      for (int kk = 0; kk < 2; ++kk)
        dst[j * 2 + kk] = *(const bf16x8*)
            &Bs[buf][wc >> 1][((((wc & 1) * 4 + pair * 2 + j) * 2 + kk) * 64 + lane) * 8];
  };

  const int nk = K >> 6;
  const int ni = nk >> 1;

  // prologue: T0 fully + T1.B halves; drain T0, leave T1.B (4 instrs) in flight
  stA(0, 0); stA(0, 1); stB(0, 0); stB(0, 1);
  stB(1, 0); stB(1, 1);
  asm volatile("s_waitcnt vmcnt(4)" ::: "memory");
  __builtin_amdgcn_s_barrier();

#pragma unroll 1
  for (int i = 0; i < ni; ++i) {
    const int tO = 2 * i + 1, tN = 2 * i + 2, tN1 = 2 * i + 3;
    const bool pfN = tN < nk, pfN1 = tN1 < nk;
    const bool steady = (i + 1 < ni);
    // ---- K-tile 2i (buf0) ----
    // p1: quadrant (m-half0, n-pair0)
    ldA(0, 0); ldB(0, 0, bA); stA(tO, 0);
    PH_SYNC(); mmaq<MH, 0, 0>(acc, aR, bA); PH_END();
    // p2: (m0, n1)
    ldB(0, 1, bB); stA(tO, 1);
    PH_SYNC(); mmaq<MH, 0, 1>(acc, aR, bB); PH_END();
    // p3: (m1, n1)
    ldA(0, 1); if (pfN) stB(tN, 0);
    PH_SYNC(); mmaq<MH, 1, 1>(acc, aR, bB); PH_END();
    // p4: (m1, n0) — no ds_reads; counted vmcnt
    if (pfN) stB(tN, 1);
    if (steady) { asm volatile("s_waitcnt vmcnt(4)" ::: "memory"); }
    else        { asm volatile("s_waitcnt vmcnt(0)" ::: "memory"); }
    PH_SYNC(); mmaq<MH, 1, 0>(acc, aR, bA); PH_END();
    // ---- K-tile 2i+1 (buf1) ----
    // p5
    ldA(1, 0); ldB(1, 0, bA); if (pfN) stA(tN, 0);
    PH_SYNC(); mmaq<MH, 0, 0>(acc, aR, bA); PH_END();
    // p6
    ldB(1, 1, bB); if (pfN) stA(tN, 1);
    PH_SYNC(); mmaq<MH, 0, 1>(acc, aR, bB); PH_END();
    // p7
    ldA(1, 1); if (pfN1) stB(tN1, 0);
    PH_SYNC(); mmaq<MH, 1, 1>(acc, aR, bB); PH_END();
    // p8
    if (pfN1) stB(tN1, 1);
    if (steady) { asm volatile("s_waitcnt vmcnt(4)" ::: "memory"); }
    else        { asm volatile("s_waitcnt vmcnt(0)" ::: "memory"); }
    PH_SYNC(); mmaq<MH, 1, 0>(acc, aR, bA); PH_END();
  }

  // epilogue; C/D layout: col = lane&15, row = (lane>>4)*4 + i   [m89-verified]
  const int r0 = m0 + wr * (BM / 2), c0 = n0 + wc * 64;
#pragma unroll
  for (int mf = 0; mf < MF; ++mf)
#pragma unroll
    for (int nf = 0; nf < 4; ++nf) {
      int r = r0 + mf * 16 + lg * 4;
      int c = c0 + nf * 16 + l15;
#pragma unroll
      for (int i = 0; i < 4; ++i) {
        float v = acc[mf][nf][i];
        if constexpr (sizeof(OutT) == 2)
          ((unsigned short*)C)[(size_t)(r + i) * N + c] = f2b(v);
        else
          ((float*)C)[(size_t)(r + i) * N + c] = v;
      }
    }
}

// ---- 128x128 GEMM (m97 structure) for the small kva matmul ----
template <typename OutT>
__global__ __launch_bounds__(256) void gemm_bt(const unsigned short* __restrict__ A,
                                               const unsigned short* __restrict__ B,
                                               OutT* __restrict__ C,
                                               int M, int N, int K) {
  __shared__ __align__(16) unsigned short As[128 * 64];
  __shared__ __align__(16) unsigned short Bs[128 * 64];
  const int tid = threadIdx.x;
  const int lane = tid & 63;
  const int w = tid >> 6;
  const int wr = w >> 1, wc = w & 1;
  const int l15 = lane & 15, lg = lane >> 4;
  const int ntn = N >> 7;
  const int bm = blockIdx.x / ntn, bn = blockIdx.x % ntn;
  const int m0 = bm << 7, n0 = bn << 7;
  const int lrow = tid >> 3;
  const int lcol = (tid & 7) << 3;

  const f32x4 zero4 = {0.f, 0.f, 0.f, 0.f};
  f32x4 acc[4][4];
#pragma unroll
  for (int i = 0; i < 4; ++i)
#pragma unroll
    for (int j = 0; j < 4; ++j) acc[i][j] = zero4;

  for (int k0 = 0; k0 < K; k0 += 64) {
#pragma unroll
    for (int j = 0; j < 4; ++j) {
      const unsigned short* ga = A + (size_t)(m0 + j * 32 + lrow) * K + (k0 + lcol);
      const unsigned short* gb = B + (size_t)(n0 + j * 32 + lrow) * K + (k0 + lcol);
      __builtin_amdgcn_global_load_lds((const AS1 void*)ga,
                                       (AS3 void*)(&As[j * 2048 + w * 512]), 16, 0, 0);
      __builtin_amdgcn_global_load_lds((const AS1 void*)gb,
                                       (AS3 void*)(&Bs[j * 2048 + w * 512]), 16, 0, 0);
    }
    __syncthreads();
#pragma unroll
    for (int kk = 0; kk < 2; ++kk) {
      bf16x8 a[4], b[4];
#pragma unroll
      for (int m = 0; m < 4; ++m)
        a[m] = *(const bf16x8*)&As[(wr * 64 + m * 16 + l15) * 64 + kk * 32 + lg * 8];
#pragma unroll
      for (int n = 0; n < 4; ++n)
        b[n] = *(const bf16x8*)&Bs[(wc * 64 + n * 16 + l15) * 64 + kk * 32 + lg * 8];
#pragma unroll
      for (int m = 0; m < 4; ++m)
#pragma unroll
        for (int n = 0; n < 4; ++n)
          acc[m][n] = __builtin_amdgcn_mfma_f32_16x16x32_bf16(a[m], b[n], acc[m][n], 0, 0, 0);
    }
    __syncthreads();
  }
  const int r0 = m0 + wr * 64, c0 = n0 + wc * 64;
#pragma unroll
  for (int m = 0; m < 4; ++m)
#pragma unroll
    for (int n = 0; n < 4; ++n) {
      int r = r0 + m * 16 + lg * 4;
      int c = c0 + n * 16 + l15;
#pragma unroll
      for (int i = 0; i < 4; ++i) {
        float v = acc[m][n][i];
        if constexpr (sizeof(OutT) == 2)
          ((unsigned short*)C)[(size_t)(r + i) * N + c] = f2b(v);
        else
          ((float*)C)[(size_t)(r + i) * N + c] = v;
      }
    }
}

// ---- RMSNorm over ckv[:, :512] -> bf16 ----
__global__ __launch_bounds__(256) void rmsnorm_k(const float* __restrict__ ckv,
                                                 const float* __restrict__ w,
                                                 unsigned short* __restrict__ out) {
  const int s = blockIdx.x;
  const int tid = threadIdx.x;
  const float* row = ckv + (size_t)s * CKVP;
  float x0 = row[tid], x1 = row[tid + 256];
  float ss = x0 * x0 + x1 * x1;
#pragma unroll
  for (int o = 1; o < 64; o <<= 1) ss += __shfl_xor(ss, o, 64);
  __shared__ float red[4];
  if ((tid & 63) == 0) red[tid >> 6] = ss;
  __syncthreads();
  float rs = rsqrtf((red[0] + red[1] + red[2] + red[3]) * (1.f / 512.f) + 1e-6f);
  out[(size_t)s * 512 + tid] = f2b(w[tid] * x0 * rs);
  out[(size_t)s * 512 + tid + 256] = f2b(w[tid + 256] * x1 * rs);
}

// ---- RoPE on q rot part (in place, bf16) ----
__global__ __launch_bounds__(256) void rope_q_k(unsigned short* __restrict__ q) {
  int idx = blockIdx.x * 256 + threadIdx.x;  // 2048*32*32
  int i = idx & 31, h = (idx >> 5) & 31, s = idx >> 10;
  float inv = exp2f(-(float)i * 0.4152410118609203f);  // 10000^(-i/32)
  float ang = (float)s * inv;
  float c = cosf(ang), sn = sinf(ang);
  size_t base = (size_t)s * QN + h * QH + 128;
  float x1 = b2f(q[base + i]), x2 = b2f(q[base + 32 + i]);
  q[base + i] = f2b(x1 * c - x2 * sn);
  q[base + 32 + i] = f2b(x2 * c + x1 * sn);
}

// ---- RoPE on shared k rot part (f32 src) -> kr bf16 (2048x64) ----
__global__ __launch_bounds__(256) void rope_k_k(const float* __restrict__ ckv,
                                                unsigned short* __restrict__ kr) {
  int idx = blockIdx.x * 256 + threadIdx.x;  // 2048*32
  int i = idx & 31, s = idx >> 5;
  float inv = exp2f(-(float)i * 0.4152410118609203f);
  float ang = (float)s * inv;
  float c = cosf(ang), sn = sinf(ang);
  const float* row = ckv + (size_t)s * CKVP + 512;
  float x1 = row[i], x2 = row[32 + i];
  kr[(size_t)s * 64 + i] = f2b(x1 * c - x2 * sn);
  kr[(size_t)s * 64 + 32 + i] = f2b(x2 * c + x1 * sn);
}

// ---- per-head V transpose: vT[h][v][t] = kv[t][h*256+128+v] ----
__global__ __launch_bounds__(256) void tv_k(const unsigned short* __restrict__ kv,
                                            unsigned short* __restrict__ vT) {
  __shared__ unsigned short t[64][66];
  const int t0 = blockIdx.x * 64, v0 = blockIdx.y * 64, h = blockIdx.z;
  const int tid = threadIdx.x;
#pragma unroll
  for (int i = 0; i < 16; ++i) {
    int idx = tid + i * 256;
    int rr = idx >> 6, cc = idx & 63;
    t[rr][cc] = kv[(size_t)(t0 + rr) * KVN + h * 256 + 128 + v0 + cc];
  }
  __syncthreads();
#pragma unroll
  for (int i = 0; i < 16; ++i) {
    int idx = tid + i * 256;
    int cc = idx >> 6, rr = idx & 63;
    vT[((size_t)h * 128 + v0 + cc) * SEQLEN + t0 + rr] = t[rr][cc];
  }
}

// ---- causal flash attention (round-2 proven structure) ----
__global__ __launch_bounds__(256) void attn_k(const unsigned short* __restrict__ q,
                                              const unsigned short* __restrict__ kv,
                                              const unsigned short* __restrict__ kr,
                                              const unsigned short* __restrict__ vT,
                                              unsigned short* __restrict__ ao) {
  __shared__ __align__(16) unsigned short Kt[64 * 192];   // 24 KB
  __shared__ __align__(16) unsigned short Vt[128 * 72];   // 18 KB
  __shared__ __align__(16) unsigned short Pl[4][32 * 72]; // 18 KB (per-wave)

  const int tid = threadIdx.x;
  const int lane = tid & 63;
  const int w = tid >> 6;
  const int l15 = lane & 15, lg = lane >> 4;
  const int sw = l15 & 7;
  const int h = blockIdx.y;
  const float scale = 0.07216878364870323f;  // 192^-0.5
  const f32x4 zero4 = {0.f, 0.f, 0.f, 0.f};

  bf16x8 kregs[4], rregs[2], vregs[4];

  auto loadregs = [&](int t0) {
#pragma unroll
    for (int p = 0; p < 4; ++p) {
      int id = tid + p * 256;
      kregs[p] = *(const bf16x8*)&kv[(size_t)(t0 + (id >> 4)) * KVN + h * 256 + (id & 15) * 8];
    }
#pragma unroll
    for (int p = 0; p < 2; ++p) {
      int id = tid + p * 256;
      rregs[p] = *(const bf16x8*)&kr[(size_t)(t0 + (id >> 3)) * 64 + (id & 7) * 8];
    }
#pragma unroll
    for (int p = 0; p < 4; ++p) {
      int id = tid + p * 256;
      vregs[p] = *(const bf16x8*)&vT[((size_t)h * 128 + (id >> 3)) * SEQLEN + t0 + (id & 7) * 8];
    }
  };
  auto writelds = [&]() {
#pragma unroll
    for (int p = 0; p < 4; ++p) {
      int id = tid + p * 256;
      int r = id >> 4, c16 = id & 15;
      *(bf16x8*)&Kt[r * 192 + ((c16 ^ (r & 7)) << 3)] = kregs[p];
    }
#pragma unroll
    for (int p = 0; p < 2; ++p) {
      int id = tid + p * 256;
      int r = id >> 3;
      *(bf16x8*)&Kt[r * 192 + ((16 + ((id & 7) ^ (r & 7))) << 3)] = rregs[p];
    }
#pragma unroll
    for (int p = 0; p < 4; ++p) {
      int id = tid + p * 256;
      *(bf16x8*)&Vt[(id >> 3) * 72 + (id & 7) * 8] = vregs[p];
    }
  };

#pragma unroll 1
  for (int pass = 0; pass < 2; ++pass) {
    const int qt = pass ? (15 - (int)blockIdx.x) : (int)blockIdx.x;
    const int n_it = 2 * qt + 2;
    const int qrow_base = qt * 128 + w * 32;

    bf16x8 qf[2][6];
#pragma unroll
    for (int m = 0; m < 2; ++m) {
      const size_t qoff = (size_t)(qrow_base + m * 16 + l15) * QN + (size_t)h * QH + lg * 8;
#pragma unroll
      for (int c = 0; c < 6; ++c) qf[m][c] = *(const bf16x8*)(q + qoff + c * 32);
    }

    f32x4 o[2][8];
    float m_r[2][4], s_r[2][4];
#pragma unroll
    for (int m = 0; m < 2; ++m) {
#pragma unroll
      for (int vt = 0; vt < 8; ++vt) o[m][vt] = zero4;
#pragma unroll
      for (int i = 0; i < 4; ++i) { m_r[m][i] = -1e30f; s_r[m][i] = 0.f; }
    }

    loadregs(0);

#pragma unroll 1
    for (int it = 0; it < n_it; ++it) {
      const int t0 = it * 64;
      writelds();
      __syncthreads();
      if (it + 1 < n_it) loadregs((it + 1) * 64);

      f32x4 st[2][4];
      __builtin_amdgcn_s_setprio(1);
#pragma unroll
      for (int tt = 0; tt < 4; ++tt) {
        f32x4 c0 = zero4, c1 = zero4;
        const int krow = (tt * 16 + l15) * 192;
#pragma unroll
        for (int c = 0; c < 6; ++c) {
          bf16x8 kf = *(const bf16x8*)&Kt[krow + (((c * 4 + lg) ^ sw) << 3)];
          c0 = __builtin_amdgcn_mfma_f32_16x16x32_bf16(qf[0][c], kf, c0, 0, 0, 0);
          c1 = __builtin_amdgcn_mfma_f32_16x16x32_bf16(qf[1][c], kf, c1, 0, 0, 0);
        }
        st[0][tt] = c0; st[1][tt] = c1;
      }
      __builtin_amdgcn_s_setprio(0);

      const bool domask = (t0 + 63 > qrow_base);
#pragma unroll
      for (int m = 0; m < 2; ++m) {
        float mt[4] = {-1e30f, -1e30f, -1e30f, -1e30f};
#pragma unroll
        for (int tt = 0; tt < 4; ++tt) {
          int tg = t0 + tt * 16 + l15;
#pragma unroll
          for (int i = 0; i < 4; ++i) {
            float v = st[m][tt][i] * scale;
            if (domask) {
              int qg = qrow_base + m * 16 + lg * 4 + i;
              v = (tg > qg) ? -1e30f : v;
            }
            st[m][tt][i] = v;
            mt[i] = fmaxf(mt[i], v);
          }
        }
#pragma unroll
        for (int off = 1; off < 16; off <<= 1)
#pragma unroll
          for (int i = 0; i < 4; ++i) mt[i] = fmaxf(mt[i], __shfl_xor(mt[i], off, 64));

        float al[4], ps[4];
#pragma unroll
        for (int i = 0; i < 4; ++i) {
          float mn = fmaxf(m_r[m][i], mt[i]);
          al[i] = __expf(m_r[m][i] - mn);
          m_r[m][i] = mn;
          ps[i] = 0.f;
        }
#pragma unroll
        for (int tt = 0; tt < 4; ++tt)
#pragma unroll
          for (int i = 0; i < 4; ++i) {
            float p = __expf(st[m][tt][i] - m_r[m][i]);
            st[m][tt][i] = p;
            ps[i] += p;
          }
#pragma unroll
        for (int off = 1; off < 16; off <<= 1)
#pragma unroll
          for (int i = 0; i < 4; ++i) ps[i] += __shfl_xor(ps[i], off, 64);
#pragma unroll
        for (int i = 0; i < 4; ++i) s_r[m][i] = s_r[m][i] * al[i] + ps[i];

#pragma unroll
        for (int tt = 0; tt < 4; ++tt)
#pragma unroll
          for (int i = 0; i < 4; ++i)
            Pl[w][(m * 16 + lg * 4 + i) * 72 + tt * 16 + l15] = f2b(st[m][tt][i]);

#pragma unroll
        for (int vt = 0; vt < 8; ++vt)
#pragma unroll
          for (int i = 0; i < 4; ++i) o[m][vt][i] *= al[i];
      }

      bf16x8 pa[2][2];
#pragma unroll
      for (int m = 0; m < 2; ++m)
#pragma unroll
        for (int ks = 0; ks < 2; ++ks)
          pa[m][ks] = *(const bf16x8*)&Pl[w][(m * 16 + l15) * 72 + ks * 32 + lg * 8];
      __builtin_amdgcn_s_setprio(1);
#pragma unroll
      for (int vt = 0; vt < 8; ++vt) {
        bf16x8 b0 = *(const bf16x8*)&Vt[(vt * 16 + l15) * 72 + lg * 8];
        bf16x8 b1 = *(const bf16x8*)&Vt[(vt * 16 + l15) * 72 + 32 + lg * 8];
#pragma unroll
        for (int m = 0; m < 2; ++m) {
          o[m][vt] = __builtin_amdgcn_mfma_f32_16x16x32_bf16(pa[m][0], b0, o[m][vt], 0, 0, 0);
          o[m][vt] = __builtin_amdgcn_mfma_f32_16x16x32_bf16(pa[m][1], b1, o[m][vt], 0, 0, 0);
        }
      }
      __builtin_amdgcn_s_setprio(0);
      __syncthreads();
    }

#pragma unroll
    for (int m = 0; m < 2; ++m)
#pragma unroll
      for (int vt = 0; vt < 8; ++vt)
#pragma unroll
        for (int i = 0; i < 4; ++i) {
          int qg = qrow_base + m * 16 + lg * 4 + i;
          int col = h * 128 + vt * 16 + l15;
          ao[(size_t)qg * (NH * 128) + col] = f2b(o[m][vt][i] / s_r[m][i]);
        }
  }
}

extern "C" void kernel_launch(void* const* d_in, const int* in_sizes, int n_in,
                              void* d_out, int out_size, void* d_ws, size_t ws_size,
                              hipStream_t stream) {
  (void)in_sizes; (void)n_in; (void)out_size; (void)ws_size;
  const float* hs = (const float*)d_in[1];
  const float* Wq = (const float*)d_in[2];
  const float* Wkva = (const float*)d_in[3];
  const float* lnw = (const float*)d_in[4];
  const float* Wkvb = (const float*)d_in[5];
  const float* Wo = (const float*)d_in[6];
  float* out = (float*)d_out;
  char* ws = (char*)d_ws;

  constexpr size_t OFF_HSBF = 0;                                    // 2048x4096 bf16
  constexpr size_t OFF_WQT = OFF_HSBF + (size_t)2048 * 4096 * 2;    // 6144x4096 bf16
  constexpr size_t OFF_WKVAT = OFF_WQT + (size_t)6144 * 4096 * 2;   // 640x4096 bf16
  constexpr size_t OFF_WKVBT = OFF_WKVAT + (size_t)640 * 4096 * 2;  // 8192x512 bf16
  constexpr size_t OFF_WOT = OFF_WKVBT + (size_t)8192 * 512 * 2;    // 4096x4096 bf16
  constexpr size_t OFF_Q = OFF_WOT + (size_t)4096 * 4096 * 2;       // 2048x6144 bf16
  constexpr size_t OFF_CKV = OFF_Q + (size_t)2048 * 6144 * 2;       // 2048x640 f32
  constexpr size_t OFF_CKVN = OFF_CKV + (size_t)2048 * 640 * 4;     // 2048x512 bf16
  constexpr size_t OFF_KR = OFF_CKVN + (size_t)2048 * 512 * 2;      // 2048x64 bf16
  constexpr size_t OFF_KV = OFF_KR + (size_t)2048 * 64 * 2;         // 2048x8192 bf16
  constexpr size_t OFF_VT = OFF_KV + (size_t)2048 * 8192 * 2;       // 32x128x2048 bf16
  constexpr size_t OFF_AO = OFF_VT + (size_t)32 * 128 * 2048 * 2;   // 2048x4096 bf16

  unsigned short* hs_bf = (unsigned short*)(ws + OFF_HSBF);
  unsigned short* WqT = (unsigned short*)(ws + OFF_WQT);
  unsigned short* WkvaT = (unsigned short*)(ws + OFF_WKVAT);
  unsigned short* WkvbT = (unsigned short*)(ws + OFF_WKVBT);
  unsigned short* WoT = (unsigned short*)(ws + OFF_WOT);
  unsigned short* qbuf = (unsigned short*)(ws + OFF_Q);
  float* ckv = (float*)(ws + OFF_CKV);
  unsigned short* ckvn = (unsigned short*)(ws + OFF_CKVN);
  unsigned short* kr = (unsigned short*)(ws + OFF_KR);
  unsigned short* kvbuf = (unsigned short*)(ws + OFF_KV);
  unsigned short* vT = (unsigned short*)(ws + OFF_VT);
  unsigned short* ao = (unsigned short*)(ws + OFF_AO);

  convk<<<dim3(8192), 256, 0, stream>>>(hs, hs_bf, 2048 * 4096 / 4);
  tconv<<<dim3(64, 96), 256, 0, stream>>>(Wq, WqT, 4096, 6144, 6144);
  tconv<<<dim3(64, 10), 256, 0, stream>>>(Wkva, WkvaT, 4096, 576, 640);
  tconv<<<dim3(8, 128), 256, 0, stream>>>(Wkvb, WkvbT, 512, 8192, 8192);
  tconv<<<dim3(64, 64), 256, 0, stream>>>(Wo, WoT, 4096, 4096, 4096);

  gemm8p<256, unsigned short><<<dim3(8 * 24), 512, 0, stream>>>(hs_bf, WqT, qbuf, 2048, 6144, 4096);
  gemm_bt<float><<<dim3(16 * 5), 256, 0, stream>>>(hs_bf, WkvaT, ckv, 2048, 640, 4096);
  rmsnorm_k<<<dim3(2048), 256, 0, stream>>>(ckv, lnw, ckvn);
  rope_k_k<<<dim3(256), 256, 0, stream>>>(ckv, kr);
  gemm8p<256, unsigned short><<<dim3(8 * 32), 512, 0, stream>>>(ckvn, WkvbT, kvbuf, 2048, 8192, 512);
  rope_q_k<<<dim3(8192), 256, 0, stream>>>(qbuf);
  tv_k<<<dim3(32, 2, 32), 256, 0, stream>>>(kvbuf, vT);
  attn_k<<<dim3(8, 32), 256, 0, stream>>>(qbuf, kvbuf, kr, vT, ao);
  gemm8p<128, float><<<dim3(16 * 16), 512, 0, stream>>>(ao, WoT, out, 2048, 4096, 4096);
}